// Round 12
// baseline (326.246 us; speedup 1.0000x reference)
//
#include <hip/hip_runtime.h>
#include <hip/hip_bf16.h>
#include <cstdint>
#include <cstddef>

#define BB 2
#define SS 2048
#define EE 1024
#define HH 16
#define MM (BB*SS)   // 4096

typedef __bf16 bf16;
typedef __bf16 bf16x8 __attribute__((ext_vector_type(8)));
typedef float f32x4 __attribute__((ext_vector_type(4)));

#define GLD16(gsrc, ldst) \
  __builtin_amdgcn_global_load_lds((const __attribute__((address_space(1))) void*)(gsrc), \
                                   (__attribute__((address_space(3))) void*)(ldst), 16, 0, 0)

// ---------------- f32 -> bf16 convert ----------------
__global__ __launch_bounds__(256) void cvt_f32_bf16(const float* __restrict__ src,
                                                    bf16* __restrict__ dst, int n) {
    int i = (blockIdx.x * 256 + threadIdx.x) * 8;
    if (i >= n) return;
    float4 a = *(const float4*)(src + i);
    float4 b = *(const float4*)(src + i + 4);
    bf16 o[8] = {(bf16)a.x,(bf16)a.y,(bf16)a.z,(bf16)a.w,
                 (bf16)b.x,(bf16)b.y,(bf16)b.z,(bf16)b.w};
    *(uint4*)(dst + i) = *(uint4*)o;
}

// convert the 4 weight matrices (each 1M elems) in one launch
__global__ __launch_bounds__(256) void cvt4(const float* __restrict__ a, const float* __restrict__ b,
                                            const float* __restrict__ c, const float* __restrict__ d,
                                            bf16* __restrict__ oa, bf16* __restrict__ ob,
                                            bf16* __restrict__ oc, bf16* __restrict__ od) {
    int sel = blockIdx.y;
    const float* s = sel == 0 ? a : sel == 1 ? b : sel == 2 ? c : d;
    bf16* o       = sel == 0 ? oa : sel == 1 ? ob : sel == 2 ? oc : od;
    int i = (blockIdx.x * 256 + threadIdx.x) * 8;
    float4 x = *(const float4*)(s + i);
    float4 y = *(const float4*)(s + i + 4);
    bf16 t[8] = {(bf16)x.x,(bf16)x.y,(bf16)x.z,(bf16)x.w,
                 (bf16)y.x,(bf16)y.y,(bf16)y.z,(bf16)y.w};
    *(uint4*)(o + i) = *(uint4*)t;
}

// ---------------- 128x128 GEMM, global_load_lds staging ----------------
template<int MODE>
__global__ __launch_bounds__(256) void gemm128(const bf16* __restrict__ A,
                                               const bf16* __restrict__ W0,
                                               const bf16* __restrict__ W1,
                                               const bf16* __restrict__ W2,
                                               const float* __restrict__ b0,
                                               const float* __restrict__ b1,
                                               const float* __restrict__ b2,
                                               void* __restrict__ o0,
                                               void* __restrict__ o1,
                                               void* __restrict__ o2) {
    __shared__ bf16 Al[128*64];
    __shared__ bf16 Bl[128*64];
    const int t = threadIdx.x;
    const int wsel = blockIdx.x >> 3;
    const int n0 = (blockIdx.x & 7) * 128;
    const int m0 = blockIdx.y * 128;
    const bf16* W  = wsel == 0 ? W0 : wsel == 1 ? W1 : W2;
    const float* bias = wsel == 0 ? b0 : wsel == 1 ? b1 : b2;
    void* outp = wsel == 0 ? o0 : wsel == 1 ? o1 : o2;

    const int w = t >> 6, lane = t & 63, lg = lane >> 4, li = lane & 15;
    const int wr = w >> 1, wc = w & 1;
    f32x4 acc[4][4] = {};

    for (int k0 = 0; k0 < 1024; k0 += 64) {
        __syncthreads();
        #pragma unroll
        for (int i = 0; i < 4; ++i) {
            int f = i * 256 + t;            // 0..1023
            int row = f >> 3, c = (f & 7) * 8;
            GLD16(A + (size_t)(m0 + row) * 1024 + k0 + c, Al + f * 8);
            GLD16(W + (size_t)(n0 + row) * 1024 + k0 + c, Bl + f * 8);
        }
        __syncthreads();
        #pragma unroll
        for (int ks = 0; ks < 2; ++ks) {
            bf16x8 af[4], bf_[4];
            #pragma unroll
            for (int m = 0; m < 4; ++m)
                af[m] = *(const bf16x8*)&Al[(wr*64 + m*16 + li)*64 + ks*32 + lg*8];
            #pragma unroll
            for (int n = 0; n < 4; ++n)
                bf_[n] = *(const bf16x8*)&Bl[(wc*64 + n*16 + li)*64 + ks*32 + lg*8];
            #pragma unroll
            for (int m = 0; m < 4; ++m)
                #pragma unroll
                for (int n = 0; n < 4; ++n)
                    acc[m][n] = __builtin_amdgcn_mfma_f32_16x16x32_bf16(af[m], bf_[n], acc[m][n], 0,0,0);
        }
    }
    #pragma unroll
    for (int m = 0; m < 4; ++m)
      #pragma unroll
      for (int n = 0; n < 4; ++n)
        #pragma unroll
        for (int r = 0; r < 4; ++r) {
            int row = m0 + wr*64 + m*16 + lg*4 + r;
            int col = n0 + wc*64 + n*16 + li;
            float v = acc[m][n][r] + bias[col];
            if (MODE == 0) {
                int b = row >> 11, s = row & (SS-1);
                int h = col >> 6, d = col & 63;
                ((bf16*)outp)[(((size_t)(b*HH + h)*SS + s) << 6) + d] = (bf16)v;
            } else {
                ((float*)outp)[(size_t)row*1024 + col] = v;
            }
        }
}

// ---------------- V transpose: [B*H][S][64] -> [B*H][64][S] ----------------
__global__ __launch_bounds__(256) void transpose_v(const bf16* __restrict__ V,
                                                   bf16* __restrict__ Vt) {
    __shared__ bf16 L[64][72];
    const int bh = blockIdx.y, s0 = blockIdx.x * 64, t = threadIdx.x;
    for (int id = t; id < 512; id += 256) {
        int row = id >> 3, c = id & 7;
        *(uint4*)&L[row][c*8] = *(const uint4*)&V[((size_t)bh*SS + s0 + row)*64 + c*8];
    }
    __syncthreads();
    for (int id = t; id < 512; id += 256) {
        int d = id >> 3, c = id & 7;
        bf16 tmp[8];
        #pragma unroll
        for (int jj = 0; jj < 8; ++jj) tmp[jj] = L[c*8 + jj][d];
        *(uint4*)&Vt[((size_t)bh*64 + d)*SS + s0 + c*8] = *(uint4*)tmp;
    }
}

// ---------------- LSUM: partial softmax row-sums over a j-half -------------
__global__ __launch_bounds__(256) void lsum_kernel(const bf16* __restrict__ Q,
                                                   const bf16* __restrict__ Kk,
                                                   float* __restrict__ Lpart) {
    __shared__ bf16 ring[2][64*64];
    __shared__ float Lred[2][64];

    const int lin = blockIdx.x + (int)(gridDim.x * blockIdx.y);
    const int nl  = (lin & 7) * 256 + (lin >> 3);   // 2048 blocks, XCD-bijective
    const int bh = nl >> 6, rr = nl & 63;
    const int qt = rr >> 1, jh2 = rr & 1;

    const int h = bh & 15;
    const int q0 = qt * 64;
    const int jbase = jh2 * 1024;
    const int t = threadIdx.x, w = t >> 6, lane = t & 63, lg = lane >> 4, li = lane & 15;
    const int jh = w & 1, qh = w >> 1;
    const float slope = exp2f(-(float)(h + 1));
    const size_t kvbase = (size_t)bh * SS * 64;
    const float L2E = 1.4426950408889634f;
    const float K1 = 0.125f * L2E;
    const float C  = slope * L2E;
    const float C64 = C * 64.f;

    bf16x8 aq[2][2];
    #pragma unroll
    for (int cbq = 0; cbq < 2; ++cbq) {
        const bf16* qptr = Q + kvbase + (size_t)(q0 + qh*32 + cbq*16 + li) * 64;
        aq[cbq][0] = *(const bf16x8*)(qptr + lg*8);
        aq[cbq][1] = *(const bf16x8*)(qptr + 32 + lg*8);
    }
    const int swz = (li & 7) << 4;

    #define STAGE_K(J0, DST) do {                                              \
        _Pragma("unroll")                                                      \
        for (int i_ = 0; i_ < 2; ++i_) {                                       \
            int f_ = i_*256 + t; int row_ = f_ >> 3, c_ = f_ & 7;              \
            GLD16(Kk + kvbase + (size_t)((J0) + row_)*64 + (c_ ^ (row_ & 7))*8,\
                  (DST) + f_*8);                                               \
        } } while (0)

    float cj[2][4];
    #pragma unroll
    for (int jt = 0; jt < 2; ++jt)
        #pragma unroll
        for (int r = 0; r < 4; ++r)
            cj[jt][r] = C * (float)(jbase + jh*32 + jt*16 + lg*4 + r - (SS-1));
    float lp[2] = {0.f, 0.f};

    STAGE_K(jbase, &ring[0][0]);
    __syncthreads();
    for (int kt = 0; kt < 16; ++kt) {
        const int cur = kt & 1;
        if (kt + 1 < 16) STAGE_K(jbase + (kt+1)*64, &ring[cur ^ 1][0]);
        const char* Ksb = (const char*)&ring[cur][0];
        bf16x8 ak[2][2];
        #pragma unroll
        for (int jt = 0; jt < 2; ++jt) {
            int row = jh*32 + jt*16 + li;
            ak[jt][0] = *(const bf16x8*)(Ksb + row*128 + ((     lg*16) ^ swz));
            ak[jt][1] = *(const bf16x8*)(Ksb + row*128 + ((64 + lg*16) ^ swz));
        }
        f32x4 sc[2][2] = {};
        __builtin_amdgcn_s_setprio(1);
        #pragma unroll
        for (int jt = 0; jt < 2; ++jt)
            #pragma unroll
            for (int cbq = 0; cbq < 2; ++cbq) {
                sc[jt][cbq] = __builtin_amdgcn_mfma_f32_16x16x32_bf16(ak[jt][0], aq[cbq][0], sc[jt][cbq], 0,0,0);
                sc[jt][cbq] = __builtin_amdgcn_mfma_f32_16x16x32_bf16(ak[jt][1], aq[cbq][1], sc[jt][cbq], 0,0,0);
            }
        __builtin_amdgcn_s_setprio(0);
        #pragma unroll
        for (int jt = 0; jt < 2; ++jt) {
            #pragma unroll
            for (int cbq = 0; cbq < 2; ++cbq)
                #pragma unroll
                for (int r = 0; r < 4; ++r)
                    lp[cbq] += __builtin_amdgcn_exp2f(fmaf(sc[jt][cbq][r], K1, cj[jt][r]));
            #pragma unroll
            for (int r = 0; r < 4; ++r) cj[jt][r] += C64;
        }
        __syncthreads();
    }
    #pragma unroll
    for (int cbq = 0; cbq < 2; ++cbq) {
        lp[cbq] += __shfl_xor(lp[cbq], 16);
        lp[cbq] += __shfl_xor(lp[cbq], 32);
    }
    if (lg == 0) {
        Lred[jh][qh*32 + li]      = lp[0];
        Lred[jh][qh*32 + 16 + li] = lp[1];
    }
    __syncthreads();
    if (t < 64)
        Lpart[((size_t)(jh2*32 + bh))*SS + q0 + t] = Lred[0][t] + Lred[1][t];
    #undef STAGE_K
}

// ---------------- LFIX: Lbuf = log2(Lpart0 + Lpart1) ------------------------
__global__ __launch_bounds__(1024) void lfix_kernel(const float* __restrict__ Lpart,
                                                    float* __restrict__ Lbuf) {
    int i = blockIdx.x * 1024 + threadIdx.x;    // 64 blocks -> 65536 = 32*2048
    Lbuf[i] = __builtin_amdgcn_logf(Lpart[i] + Lpart[65536 + i]);
}

// ---------------- FAT: weights tiles (single-shot) + PV blocks --------------
// id%5==4 -> PV block (2048): R11 wpv minus weight stores.
// else    -> weights block (8192): one 128x128 q-x-j tile, K-dim=64 in ONE
//            shot: stage Q/K tiles, 1 barrier, 32 MFMA + exp2 + f32x4 stores,
//            NO further barriers -> stores free-stream.
__global__ __launch_bounds__(256) void fat_kernel(const bf16* __restrict__ Q,
                                                  const bf16* __restrict__ Kk,
                                                  const bf16* __restrict__ Vt,
                                                  const float* __restrict__ Lbuf,
                                                  float* __restrict__ wout,
                                                  bf16* __restrict__ opart0,
                                                  bf16* __restrict__ opart1) {
    __shared__ bf16 lds[4][64*64];   // 32 KB
    const int id = blockIdx.x;
    const int t = threadIdx.x, w = t >> 6, lane = t & 63, lg = lane >> 4, li = lane & 15;
    const float L2E = 1.4426950408889634f;
    const float K1 = 0.125f * L2E;
    const int swz = (li & 7) << 4;

    if (id % 5 != 4) {
        // ================= WEIGHTS TILE =================
        const int wi = (id / 5) * 4 + (id % 5);       // 0..8191
        const int bh = wi >> 8, tile = wi & 255;
        const int q0 = (tile >> 4) * 128, j0 = (tile & 15) * 128;
        const int h = bh & 15;
        const float slope = exp2f(-(float)(h + 1));
        const float C = slope * L2E;
        const size_t kvbase = (size_t)bh * SS * 64;
        const int wj = w & 1, wq = w >> 1;

        bf16* Qt = &lds[0][0];    // 128 rows x 128 B
        bf16* Kt = &lds[2][0];
        #pragma unroll
        for (int i = 0; i < 4; ++i) {
            int f = i * 256 + t; int row = f >> 3, c16 = f & 7;
            GLD16(Q  + kvbase + (size_t)(q0 + row)*64 + (c16 ^ (row & 7))*8, Qt + f*8);
            GLD16(Kk + kvbase + (size_t)(j0 + row)*64 + (c16 ^ (row & 7))*8, Kt + f*8);
        }
        __syncthreads();

        const char* Qtb = (const char*)Qt;
        const char* Ktb = (const char*)Kt;
        bf16x8 aq[4][2];
        float lgl[4];
        #pragma unroll
        for (int qt = 0; qt < 4; ++qt) {
            int rl = wq*64 + qt*16 + li;
            aq[qt][0] = *(const bf16x8*)(Qtb + rl*128 + ((     lg*16) ^ swz));
            aq[qt][1] = *(const bf16x8*)(Qtb + rl*128 + ((64 + lg*16) ^ swz));
            lgl[qt] = Lbuf[(size_t)bh*SS + q0 + rl];
        }
        #pragma unroll
        for (int jt = 0; jt < 4; ++jt) {
            int rl = wj*64 + jt*16 + li;
            bf16x8 ak0 = *(const bf16x8*)(Ktb + rl*128 + ((     lg*16) ^ swz));
            bf16x8 ak1 = *(const bf16x8*)(Ktb + rl*128 + ((64 + lg*16) ^ swz));
            f32x4 sc[4] = {};
            __builtin_amdgcn_s_setprio(1);
            #pragma unroll
            for (int qt = 0; qt < 4; ++qt) {
                sc[qt] = __builtin_amdgcn_mfma_f32_16x16x32_bf16(ak0, aq[qt][0], sc[qt], 0,0,0);
                sc[qt] = __builtin_amdgcn_mfma_f32_16x16x32_bf16(ak1, aq[qt][1], sc[qt], 0,0,0);
            }
            __builtin_amdgcn_s_setprio(0);
            const float cjb = C * (float)(j0 + wj*64 + jt*16 + lg*4 - (SS-1));
            #pragma unroll
            for (int qt = 0; qt < 4; ++qt) {
                f32x4 v;
                v[0] = __builtin_amdgcn_exp2f(fmaf(sc[qt][0], K1, cjb           - lgl[qt]));
                v[1] = __builtin_amdgcn_exp2f(fmaf(sc[qt][1], K1, cjb + C       - lgl[qt]));
                v[2] = __builtin_amdgcn_exp2f(fmaf(sc[qt][2], K1, cjb + C*2.f   - lgl[qt]));
                v[3] = __builtin_amdgcn_exp2f(fmaf(sc[qt][3], K1, cjb + C*3.f   - lgl[qt]));
                float* wr_ = wout + ((size_t)bh*SS + q0 + wq*64 + qt*16 + li) * SS
                                  + j0 + wj*64 + jt*16 + lg*4;
                *(f32x4*)wr_ = v;
            }
        }
        return;
    }

    // ================= PV BLOCK (R11 wpv minus weight stores) =================
    const int nl = id / 5;                       // 0..2047
    const int bh = nl >> 6, rr = nl & 63;
    const int qt = rr >> 1, jh2 = rr & 1;
    const int b = bh >> 4, h = bh & 15;
    const int q0 = qt * 64;
    const int jbase = jh2 * 1024;
    const int jh = w & 1, qh = w >> 1;
    const float slope = exp2f(-(float)(h + 1));
    const size_t kvbase = (size_t)bh * SS * 64;
    const size_t vtbase = (size_t)bh * 64 * SS;
    const float C  = slope * L2E;
    const float C64 = C * 64.f;
    bf16* opart = jh2 == 0 ? opart0 : opart1;
    bf16 (*ring)[64*64] = lds;

    bf16x8 aq[2][2];
    float lgl[2];
    #pragma unroll
    for (int cbq = 0; cbq < 2; ++cbq) {
        const int qi = q0 + qh*32 + cbq*16 + li;
        const bf16* qptr = Q + kvbase + (size_t)qi * 64;
        aq[cbq][0] = *(const bf16x8*)(qptr + lg*8);
        aq[cbq][1] = *(const bf16x8*)(qptr + 32 + lg*8);
        lgl[cbq] = Lbuf[(size_t)bh*SS + qi];
    }

    #define STAGE_K(J0, DST) do {                                              \
        _Pragma("unroll")                                                      \
        for (int i_ = 0; i_ < 2; ++i_) {                                       \
            int f_ = i_*256 + t; int row_ = f_ >> 3, c_ = f_ & 7;              \
            GLD16(Kk + kvbase + (size_t)((J0) + row_)*64 + (c_ ^ (row_ & 7))*8,\
                  (DST) + f_*8);                                               \
        } } while (0)
    #define STAGE_V(J0, DST) do {                                              \
        _Pragma("unroll")                                                      \
        for (int i_ = 0; i_ < 2; ++i_) {                                       \
            int f_ = i_*256 + t; int row_ = f_ >> 3, c_ = f_ & 7;              \
            GLD16(Vt + vtbase + (size_t)row_*SS + (J0) + (c_ ^ (row_ & 7))*8,  \
                  (DST) + f_*8);                                               \
        } } while (0)

    float ecr[2][2][4];
    #pragma unroll
    for (int jt = 0; jt < 2; ++jt)
        #pragma unroll
        for (int cbq = 0; cbq < 2; ++cbq)
            #pragma unroll
            for (int r = 0; r < 4; ++r)
                ecr[jt][cbq][r] = C * (float)(jbase + jh*32 + jt*16 + lg*4 + r - (SS-1)) - lgl[cbq];

    f32x4 acc[2][4] = {};

    STAGE_K(jbase, &ring[0][0]);
    STAGE_V(jbase, &ring[2][0]);
    __syncthreads();
    for (int kt = 0; kt < 16; ++kt) {
        const int cur = kt & 1;
        const int j0 = jbase + kt * 64;
        if (kt + 1 < 16) {
            STAGE_K(j0 + 64, &ring[cur ^ 1][0]);
            STAGE_V(j0 + 64, &ring[2 + (cur ^ 1)][0]);
        }
        const char* Ksb = (const char*)&ring[cur][0];
        const char* Vsb = (const char*)&ring[2 + cur][0];
        bf16x8 ak[2][2];
        #pragma unroll
        for (int jt = 0; jt < 2; ++jt) {
            int row = jh*32 + jt*16 + li;
            ak[jt][0] = *(const bf16x8*)(Ksb + row*128 + ((     lg*16) ^ swz));
            ak[jt][1] = *(const bf16x8*)(Ksb + row*128 + ((64 + lg*16) ^ swz));
        }
        f32x4 sc[2][2] = {};
        __builtin_amdgcn_s_setprio(1);
        #pragma unroll
        for (int jt = 0; jt < 2; ++jt)
            #pragma unroll
            for (int cbq = 0; cbq < 2; ++cbq) {
                sc[jt][cbq] = __builtin_amdgcn_mfma_f32_16x16x32_bf16(ak[jt][0], aq[cbq][0], sc[jt][cbq], 0,0,0);
                sc[jt][cbq] = __builtin_amdgcn_mfma_f32_16x16x32_bf16(ak[jt][1], aq[cbq][1], sc[jt][cbq], 0,0,0);
            }
        __builtin_amdgcn_s_setprio(0);
        bf16x8 pa[2];
        #pragma unroll
        for (int cbq = 0; cbq < 2; ++cbq) {
            bf16x8 p;
            #pragma unroll
            for (int jt = 0; jt < 2; ++jt) {
                p[jt*4+0] = (bf16)__builtin_amdgcn_exp2f(fmaf(sc[jt][cbq][0], K1, ecr[jt][cbq][0]));
                p[jt*4+1] = (bf16)__builtin_amdgcn_exp2f(fmaf(sc[jt][cbq][1], K1, ecr[jt][cbq][1]));
                p[jt*4+2] = (bf16)__builtin_amdgcn_exp2f(fmaf(sc[jt][cbq][2], K1, ecr[jt][cbq][2]));
                p[jt*4+3] = (bf16)__builtin_amdgcn_exp2f(fmaf(sc[jt][cbq][3], K1, ecr[jt][cbq][3]));
            }
            pa[cbq] = p;
        }
        #pragma unroll
        for (int jt = 0; jt < 2; ++jt)
            #pragma unroll
            for (int cbq = 0; cbq < 2; ++cbq) {
                ecr[jt][cbq][0] += C64; ecr[jt][cbq][1] += C64;
                ecr[jt][cbq][2] += C64; ecr[jt][cbq][3] += C64;
            }
        bf16x8 vb[4];
        #pragma unroll
        for (int d0 = 0; d0 < 4; ++d0) {
            int row = d0*16 + li;
            uint2 u0 = *(const uint2*)(Vsb + row*128 + ((jh*64      + lg*8) ^ swz));
            uint2 u1 = *(const uint2*)(Vsb + row*128 + ((jh*64 + 32 + lg*8) ^ swz));
            uint4 uu = {u0.x, u0.y, u1.x, u1.y};
            vb[d0] = __builtin_bit_cast(bf16x8, uu);
        }
        __builtin_amdgcn_s_setprio(1);
        #pragma unroll
        for (int cbq = 0; cbq < 2; ++cbq)
            #pragma unroll
            for (int d0 = 0; d0 < 4; ++d0)
                acc[cbq][d0] = __builtin_amdgcn_mfma_f32_16x16x32_bf16(pa[cbq], vb[d0], acc[cbq][d0], 0,0,0);
        __builtin_amdgcn_s_setprio(0);
        __syncthreads();
    }

    bf16* Obuf = &ring[0][0];
    #pragma unroll
    for (int cbq = 0; cbq < 2; ++cbq)
        #pragma unroll
        for (int d0 = 0; d0 < 4; ++d0)
            #pragma unroll
            for (int r = 0; r < 4; ++r)
                Obuf[jh*4096 + (qh*32 + cbq*16 + lg*4 + r)*64 + d0*16 + li] =
                    (bf16)acc[cbq][d0][r];
    __syncthreads();
    {
        int q = t >> 2, dc = (t & 3) << 4;
        const bf16* o0 = Obuf +        q*64 + dc;
        const bf16* o1 = Obuf + 4096 + q*64 + dc;
        bf16x8 a0 = *(const bf16x8*)(o0),     a1 = *(const bf16x8*)(o0 + 8);
        bf16x8 b0 = *(const bf16x8*)(o1),     b1 = *(const bf16x8*)(o1 + 8);
        bf16 ov[16];
        #pragma unroll
        for (int e = 0; e < 8; ++e) {
            ov[e]     = (bf16)((float)a0[e] + (float)b0[e]);
            ov[8 + e] = (bf16)((float)a1[e] + (float)b1[e]);
        }
        bf16* dst = opart + ((size_t)(b*SS + q0 + q))*EE + h*64 + dc;
        *(uint4*)(dst)     = *(uint4*)(ov);
        *(uint4*)(dst + 8) = *(uint4*)(ov + 8);
    }
    #undef STAGE_K
    #undef STAGE_V
}

// ---------------- ORED: Ab = Opart0 + Opart1 (bf16, x8 vectorized) ----------
__global__ __launch_bounds__(256) void ored_kernel(const bf16* __restrict__ O0,
                                                   const bf16* __restrict__ O1,
                                                   bf16* __restrict__ Ab) {
    int i = (blockIdx.x * 256 + threadIdx.x) * 8;   // 2048 blocks -> 4.19M elems
    bf16x8 a = *(const bf16x8*)(O0 + i);
    bf16x8 b = *(const bf16x8*)(O1 + i);
    bf16 o[8];
    #pragma unroll
    for (int e = 0; e < 8; ++e) o[e] = (bf16)((float)a[e] + (float)b[e]);
    *(uint4*)(Ab + i) = *(uint4*)o;
}

// ---------------- launcher ----------------
extern "C" void kernel_launch(void* const* d_in, const int* in_sizes, int n_in,
                              void* d_out, int out_size, void* d_ws, size_t ws_size,
                              hipStream_t stream) {
    const float* x   = (const float*)d_in[0];
    const float* Wq  = (const float*)d_in[1];
    const float* bq  = (const float*)d_in[2];
    const float* Wk  = (const float*)d_in[3];
    const float* bk  = (const float*)d_in[4];
    const float* Wv  = (const float*)d_in[5];
    const float* bv  = (const float*)d_in[6];
    const float* Wfc = (const float*)d_in[7];
    const float* bfc = (const float*)d_in[8];

    char* ws = (char*)d_ws;
    const size_t MB = 1024u*1024u;
    bf16* xb   = (bf16*)(ws + 0);        // 8 MB; dead after QKV -> Opart0
    bf16* wqb  = (bf16*)(ws + 8*MB);     // 2 MB; dead after QKV -> Lpart/Lbuf
    bf16* wkb  = (bf16*)(ws + 10*MB);
    bf16* wvb  = (bf16*)(ws + 12*MB);
    bf16* wfb  = (bf16*)(ws + 14*MB);    // alive until fc
    bf16* Qb   = (bf16*)(ws + 16*MB);    // 8 MB  [B*H][S][64]
    bf16* Kb   = (bf16*)(ws + 24*MB);    // 8 MB
    bf16* Vb   = (bf16*)(ws + 32*MB);    // 8 MB; dead after transpose -> Opart1
    bf16* Vtb  = (bf16*)(ws + 40*MB);    // 8 MB  [B*H][64][S]
    bf16* Ab   = (bf16*)(ws + 48*MB);    // 8 MB  [B][S][E]
    bf16* Opart0 = (bf16*)(ws + 0);      // reuse xb
    bf16* Opart1 = (bf16*)(ws + 32*MB);  // reuse Vb
    float* Lpart = (float*)(ws + 8*MB);  // 512 KB (reuse wqb)
    float* Lb    = (float*)(ws + 9*MB);  // 256 KB (reuse wqb tail)

    float* outp = (float*)d_out;
    float* wout = outp + (size_t)BB*SS*EE;

    cvt_f32_bf16<<<dim3(4194304/8/256), 256, 0, stream>>>(x, xb, 4194304);
    cvt4<<<dim3(512, 4), 256, 0, stream>>>(Wq, Wk, Wv, Wfc, wqb, wkb, wvb, wfb);

    gemm128<0><<<dim3(24, 32), 256, 0, stream>>>(xb, wqb, wkb, wvb, bq, bk, bv, Qb, Kb, Vb);

    transpose_v<<<dim3(SS/64, BB*HH), 256, 0, stream>>>(Vb, Vtb);

    lsum_kernel<<<dim3(64, 32), 256, 0, stream>>>(Qb, Kb, Lpart);
    lfix_kernel<<<dim3(64), 1024, 0, stream>>>(Lpart, Lb);

    fat_kernel<<<dim3(10240), 256, 0, stream>>>(Qb, Kb, Vtb, Lb, wout, Opart0, Opart1);

    ored_kernel<<<dim3(2048), 256, 0, stream>>>(Opart0, Opart1, Ab);

    gemm128<1><<<dim3(8, 32), 256, 0, stream>>>(Ab, wfb, wfb, wfb, bfc, bfc, bfc, d_out, d_out, d_out);
}

// Round 13
// 299.493 us; speedup vs baseline: 1.0893x; 1.0893x over previous
//
#include <hip/hip_runtime.h>
#include <hip/hip_bf16.h>
#include <cstdint>
#include <cstddef>

#define BB 2
#define SS 2048
#define EE 1024
#define HH 16
#define MM (BB*SS)   // 4096

typedef __bf16 bf16;
typedef __bf16 bf16x8 __attribute__((ext_vector_type(8)));
typedef float f32x4 __attribute__((ext_vector_type(4)));

#define GLD16(gsrc, ldst) \
  __builtin_amdgcn_global_load_lds((const __attribute__((address_space(1))) void*)(gsrc), \
                                   (__attribute__((address_space(3))) void*)(ldst), 16, 0, 0)

// ---------------- f32 -> bf16 convert ----------------
__global__ __launch_bounds__(256) void cvt_f32_bf16(const float* __restrict__ src,
                                                    bf16* __restrict__ dst, int n) {
    int i = (blockIdx.x * 256 + threadIdx.x) * 8;
    if (i >= n) return;
    float4 a = *(const float4*)(src + i);
    float4 b = *(const float4*)(src + i + 4);
    bf16 o[8] = {(bf16)a.x,(bf16)a.y,(bf16)a.z,(bf16)a.w,
                 (bf16)b.x,(bf16)b.y,(bf16)b.z,(bf16)b.w};
    *(uint4*)(dst + i) = *(uint4*)o;
}

// convert the 4 weight matrices (each 1M elems) in one launch
__global__ __launch_bounds__(256) void cvt4(const float* __restrict__ a, const float* __restrict__ b,
                                            const float* __restrict__ c, const float* __restrict__ d,
                                            bf16* __restrict__ oa, bf16* __restrict__ ob,
                                            bf16* __restrict__ oc, bf16* __restrict__ od) {
    int sel = blockIdx.y;
    const float* s = sel == 0 ? a : sel == 1 ? b : sel == 2 ? c : d;
    bf16* o       = sel == 0 ? oa : sel == 1 ? ob : sel == 2 ? oc : od;
    int i = (blockIdx.x * 256 + threadIdx.x) * 8;
    float4 x = *(const float4*)(s + i);
    float4 y = *(const float4*)(s + i + 4);
    bf16 t[8] = {(bf16)x.x,(bf16)x.y,(bf16)x.z,(bf16)x.w,
                 (bf16)y.x,(bf16)y.y,(bf16)y.z,(bf16)y.w};
    *(uint4*)(o + i) = *(uint4*)t;
}

// ---------------- 128x128 GEMM, global_load_lds staging ----------------
template<int MODE>
__global__ __launch_bounds__(256) void gemm128(const bf16* __restrict__ A,
                                               const bf16* __restrict__ W0,
                                               const bf16* __restrict__ W1,
                                               const bf16* __restrict__ W2,
                                               const float* __restrict__ b0,
                                               const float* __restrict__ b1,
                                               const float* __restrict__ b2,
                                               void* __restrict__ o0,
                                               void* __restrict__ o1,
                                               void* __restrict__ o2) {
    __shared__ bf16 Al[128*64];
    __shared__ bf16 Bl[128*64];
    const int t = threadIdx.x;
    const int wsel = blockIdx.x >> 3;
    const int n0 = (blockIdx.x & 7) * 128;
    const int m0 = blockIdx.y * 128;
    const bf16* W  = wsel == 0 ? W0 : wsel == 1 ? W1 : W2;
    const float* bias = wsel == 0 ? b0 : wsel == 1 ? b1 : b2;
    void* outp = wsel == 0 ? o0 : wsel == 1 ? o1 : o2;

    const int w = t >> 6, lane = t & 63, lg = lane >> 4, li = lane & 15;
    const int wr = w >> 1, wc = w & 1;
    f32x4 acc[4][4] = {};

    for (int k0 = 0; k0 < 1024; k0 += 64) {
        __syncthreads();
        #pragma unroll
        for (int i = 0; i < 4; ++i) {
            int f = i * 256 + t;            // 0..1023
            int row = f >> 3, c = (f & 7) * 8;
            GLD16(A + (size_t)(m0 + row) * 1024 + k0 + c, Al + f * 8);
            GLD16(W + (size_t)(n0 + row) * 1024 + k0 + c, Bl + f * 8);
        }
        __syncthreads();
        #pragma unroll
        for (int ks = 0; ks < 2; ++ks) {
            bf16x8 af[4], bf_[4];
            #pragma unroll
            for (int m = 0; m < 4; ++m)
                af[m] = *(const bf16x8*)&Al[(wr*64 + m*16 + li)*64 + ks*32 + lg*8];
            #pragma unroll
            for (int n = 0; n < 4; ++n)
                bf_[n] = *(const bf16x8*)&Bl[(wc*64 + n*16 + li)*64 + ks*32 + lg*8];
            #pragma unroll
            for (int m = 0; m < 4; ++m)
                #pragma unroll
                for (int n = 0; n < 4; ++n)
                    acc[m][n] = __builtin_amdgcn_mfma_f32_16x16x32_bf16(af[m], bf_[n], acc[m][n], 0,0,0);
        }
    }
    #pragma unroll
    for (int m = 0; m < 4; ++m)
      #pragma unroll
      for (int n = 0; n < 4; ++n)
        #pragma unroll
        for (int r = 0; r < 4; ++r) {
            int row = m0 + wr*64 + m*16 + lg*4 + r;
            int col = n0 + wc*64 + n*16 + li;
            float v = acc[m][n][r] + bias[col];
            if (MODE == 0) {
                int b = row >> 11, s = row & (SS-1);
                int h = col >> 6, d = col & 63;
                ((bf16*)outp)[(((size_t)(b*HH + h)*SS + s) << 6) + d] = (bf16)v;
            } else {
                ((float*)outp)[(size_t)row*1024 + col] = v;
            }
        }
}

// ---------------- V transpose: [B*H][S][64] -> [B*H][64][S] ----------------
__global__ __launch_bounds__(256) void transpose_v(const bf16* __restrict__ V,
                                                   bf16* __restrict__ Vt) {
    __shared__ bf16 L[64][72];
    const int bh = blockIdx.y, s0 = blockIdx.x * 64, t = threadIdx.x;
    for (int id = t; id < 512; id += 256) {
        int row = id >> 3, c = id & 7;
        *(uint4*)&L[row][c*8] = *(const uint4*)&V[((size_t)bh*SS + s0 + row)*64 + c*8];
    }
    __syncthreads();
    for (int id = t; id < 512; id += 256) {
        int d = id >> 3, c = id & 7;
        bf16 tmp[8];
        #pragma unroll
        for (int jj = 0; jj < 8; ++jj) tmp[jj] = L[c*8 + jj][d];
        *(uint4*)&Vt[((size_t)bh*64 + d)*SS + s0 + c*8] = *(uint4*)tmp;
    }
}

// ---------------- LSUM: partial softmax row-sums over a j-half -------------
__global__ __launch_bounds__(256) void lsum_kernel(const bf16* __restrict__ Q,
                                                   const bf16* __restrict__ Kk,
                                                   float* __restrict__ Lpart) {
    __shared__ bf16 ring[2][64*64];
    __shared__ float Lred[2][64];

    const int lin = blockIdx.x + (int)(gridDim.x * blockIdx.y);
    const int nl  = (lin & 7) * 256 + (lin >> 3);   // 2048 blocks, XCD-bijective
    const int bh = nl >> 6, rr = nl & 63;
    const int qt = rr >> 1, jh2 = rr & 1;

    const int h = bh & 15;
    const int q0 = qt * 64;
    const int jbase = jh2 * 1024;
    const int t = threadIdx.x, w = t >> 6, lane = t & 63, lg = lane >> 4, li = lane & 15;
    const int jh = w & 1, qh = w >> 1;
    const float slope = exp2f(-(float)(h + 1));
    const size_t kvbase = (size_t)bh * SS * 64;
    const float L2E = 1.4426950408889634f;
    const float K1 = 0.125f * L2E;
    const float C  = slope * L2E;
    const float C64 = C * 64.f;

    bf16x8 aq[2][2];
    #pragma unroll
    for (int cbq = 0; cbq < 2; ++cbq) {
        const bf16* qptr = Q + kvbase + (size_t)(q0 + qh*32 + cbq*16 + li) * 64;
        aq[cbq][0] = *(const bf16x8*)(qptr + lg*8);
        aq[cbq][1] = *(const bf16x8*)(qptr + 32 + lg*8);
    }
    const int swz = (li & 7) << 4;

    #define STAGE_K(J0, DST) do {                                              \
        _Pragma("unroll")                                                      \
        for (int i_ = 0; i_ < 2; ++i_) {                                       \
            int f_ = i_*256 + t; int row_ = f_ >> 3, c_ = f_ & 7;              \
            GLD16(Kk + kvbase + (size_t)((J0) + row_)*64 + (c_ ^ (row_ & 7))*8,\
                  (DST) + f_*8);                                               \
        } } while (0)

    float cj[2][4];
    #pragma unroll
    for (int jt = 0; jt < 2; ++jt)
        #pragma unroll
        for (int r = 0; r < 4; ++r)
            cj[jt][r] = C * (float)(jbase + jh*32 + jt*16 + lg*4 + r - (SS-1));
    float lp[2] = {0.f, 0.f};

    STAGE_K(jbase, &ring[0][0]);
    __syncthreads();
    for (int kt = 0; kt < 16; ++kt) {
        const int cur = kt & 1;
        if (kt + 1 < 16) STAGE_K(jbase + (kt+1)*64, &ring[cur ^ 1][0]);
        const char* Ksb = (const char*)&ring[cur][0];
        bf16x8 ak[2][2];
        #pragma unroll
        for (int jt = 0; jt < 2; ++jt) {
            int row = jh*32 + jt*16 + li;
            ak[jt][0] = *(const bf16x8*)(Ksb + row*128 + ((     lg*16) ^ swz));
            ak[jt][1] = *(const bf16x8*)(Ksb + row*128 + ((64 + lg*16) ^ swz));
        }
        f32x4 sc[2][2] = {};
        __builtin_amdgcn_s_setprio(1);
        #pragma unroll
        for (int jt = 0; jt < 2; ++jt)
            #pragma unroll
            for (int cbq = 0; cbq < 2; ++cbq) {
                sc[jt][cbq] = __builtin_amdgcn_mfma_f32_16x16x32_bf16(ak[jt][0], aq[cbq][0], sc[jt][cbq], 0,0,0);
                sc[jt][cbq] = __builtin_amdgcn_mfma_f32_16x16x32_bf16(ak[jt][1], aq[cbq][1], sc[jt][cbq], 0,0,0);
            }
        __builtin_amdgcn_s_setprio(0);
        #pragma unroll
        for (int jt = 0; jt < 2; ++jt) {
            #pragma unroll
            for (int cbq = 0; cbq < 2; ++cbq)
                #pragma unroll
                for (int r = 0; r < 4; ++r)
                    lp[cbq] += __builtin_amdgcn_exp2f(fmaf(sc[jt][cbq][r], K1, cj[jt][r]));
            #pragma unroll
            for (int r = 0; r < 4; ++r) cj[jt][r] += C64;
        }
        __syncthreads();
    }
    #pragma unroll
    for (int cbq = 0; cbq < 2; ++cbq) {
        lp[cbq] += __shfl_xor(lp[cbq], 16);
        lp[cbq] += __shfl_xor(lp[cbq], 32);
    }
    if (lg == 0) {
        Lred[jh][qh*32 + li]      = lp[0];
        Lred[jh][qh*32 + 16 + li] = lp[1];
    }
    __syncthreads();
    if (t < 64)
        Lpart[((size_t)(jh2*32 + bh))*SS + q0 + t] = Lred[0][t] + Lred[1][t];
    #undef STAGE_K
}

// ---------------- LFIX: Lbuf = log2(Lpart0 + Lpart1) ------------------------
__global__ __launch_bounds__(1024) void lfix_kernel(const float* __restrict__ Lpart,
                                                    float* __restrict__ Lbuf) {
    int i = blockIdx.x * 1024 + threadIdx.x;    // 64 blocks -> 65536 = 32*2048
    Lbuf[i] = __builtin_amdgcn_logf(Lpart[i] + Lpart[65536 + i]);
}

// ---------------- FAT: weights tiles (LDS-transposed stores) + PV blocks ----
// id%5==4 -> PV block (2048): unchanged from R12.
// else    -> weights block (8192): one 128x128 tile. NEW: P goes through a
//            swizzled 32KB LDS tile; stores are 4 rows x 256B contiguous
//            spans per instruction (fill-kernel-like), never drained.
__global__ __launch_bounds__(256) void fat_kernel(const bf16* __restrict__ Q,
                                                  const bf16* __restrict__ Kk,
                                                  const bf16* __restrict__ Vt,
                                                  const float* __restrict__ Lbuf,
                                                  float* __restrict__ wout,
                                                  bf16* __restrict__ opart0,
                                                  bf16* __restrict__ opart1) {
    __shared__ bf16 lds[4][64*64];   // 32 KB
    const int id = blockIdx.x;
    const int t = threadIdx.x, w = t >> 6, lane = t & 63, lg = lane >> 4, li = lane & 15;
    const float L2E = 1.4426950408889634f;
    const float K1 = 0.125f * L2E;
    const int swz = (li & 7) << 4;

    if (id % 5 != 4) {
        // ================= WEIGHTS TILE =================
        const int wi = (id / 5) * 4 + (id % 5);       // 0..8191
        const int bh = wi >> 8, tile = wi & 255;
        const int q0 = (tile >> 4) * 128, j0 = (tile & 15) * 128;
        const int h = bh & 15;
        const float slope = exp2f(-(float)(h + 1));
        const float C = slope * L2E;
        const size_t kvbase = (size_t)bh * SS * 64;

        bf16* Qt = &lds[0][0];    // 16 KB
        bf16* Kt = &lds[2][0];    // 16 KB
        #pragma unroll
        for (int i = 0; i < 4; ++i) {
            int f = i * 256 + t; int row = f >> 3, c16 = f & 7;
            GLD16(Q  + kvbase + (size_t)(q0 + row)*64 + (c16 ^ (row & 7))*8, Qt + f*8);
            GLD16(Kk + kvbase + (size_t)(j0 + row)*64 + (c16 ^ (row & 7))*8, Kt + f*8);
        }
        __syncthreads();

        const char* Qtb = (const char*)Qt;
        const char* Ktb = (const char*)Kt;
        // Q frags: q = q0 + w*32 + qt2*16 + li  (wave owns 32 q-rows)
        bf16x8 aq[2][2];
        float lgl[2];
        #pragma unroll
        for (int qt2 = 0; qt2 < 2; ++qt2) {
            int rl = w*32 + qt2*16 + li;
            aq[qt2][0] = *(const bf16x8*)(Qtb + rl*128 + ((     lg*16) ^ swz));
            aq[qt2][1] = *(const bf16x8*)(Qtb + rl*128 + ((64 + lg*16) ^ swz));
            lgl[qt2] = Lbuf[(size_t)bh*SS + q0 + rl];
        }
        // K frags: preload ALL 8 j-strips so Kt can be overwritten by Pf
        bf16x8 ak[8][2];
        #pragma unroll
        for (int s8 = 0; s8 < 8; ++s8) {
            int rl = s8*16 + li;
            ak[s8][0] = *(const bf16x8*)(Ktb + rl*128 + ((     lg*16) ^ swz));
            ak[s8][1] = *(const bf16x8*)(Ktb + rl*128 + ((64 + lg*16) ^ swz));
        }
        asm volatile("s_waitcnt lgkmcnt(0)" ::: "memory");
        __builtin_amdgcn_sched_barrier(0);
        __builtin_amdgcn_s_barrier();

        float* Pf = (float*)&lds[0][0];   // 32 KB: [128 q][64 j] f32, swizzled
        #pragma unroll
        for (int half = 0; half < 2; ++half) {
            #pragma unroll
            for (int jt = 0; jt < 4; ++jt) {
                const int s8 = half*4 + jt;
                f32x4 sc[2] = {};
                __builtin_amdgcn_s_setprio(1);
                #pragma unroll
                for (int qt2 = 0; qt2 < 2; ++qt2) {
                    sc[qt2] = __builtin_amdgcn_mfma_f32_16x16x32_bf16(ak[s8][0], aq[qt2][0], sc[qt2], 0,0,0);
                    sc[qt2] = __builtin_amdgcn_mfma_f32_16x16x32_bf16(ak[s8][1], aq[qt2][1], sc[qt2], 0,0,0);
                }
                __builtin_amdgcn_s_setprio(0);
                const float cjb = C * (float)(j0 + half*64 + jt*16 + lg*4 - (SS-1));
                #pragma unroll
                for (int qt2 = 0; qt2 < 2; ++qt2) {
                    f32x4 v;
                    v[0] = __builtin_amdgcn_exp2f(fmaf(sc[qt2][0], K1, cjb         - lgl[qt2]));
                    v[1] = __builtin_amdgcn_exp2f(fmaf(sc[qt2][1], K1, cjb + C     - lgl[qt2]));
                    v[2] = __builtin_amdgcn_exp2f(fmaf(sc[qt2][2], K1, cjb + C*2.f - lgl[qt2]));
                    v[3] = __builtin_amdgcn_exp2f(fmaf(sc[qt2][3], K1, cjb + C*3.f - lgl[qt2]));
                    const int q = w*32 + qt2*16 + li;
                    const int jb4 = (jt*16 + lg*4) * 4;               // byte within 256B row
                    *(f32x4*)((char*)Pf + q*256 + (jb4 ^ ((q & 15) << 4))) = v;
                }
            }
            asm volatile("s_waitcnt lgkmcnt(0)" ::: "memory");
            __builtin_amdgcn_sched_barrier(0);
            __builtin_amdgcn_s_barrier();
            // store phase: per instruction 4 rows x 256B contiguous spans
            #pragma unroll
            for (int i = 0; i < 8; ++i) {
                const int r = w*32 + i*4 + (lane >> 4);
                const int s = lane & 15;
                f32x4 v = *(const f32x4*)((const char*)Pf + r*256 + ((s*16) ^ ((r & 15) << 4)));
                *(f32x4*)(wout + ((size_t)bh*SS + q0 + r)*SS + j0 + half*64 + s*4) = v;
            }
            asm volatile("s_waitcnt lgkmcnt(0)" ::: "memory");
            __builtin_amdgcn_sched_barrier(0);
            __builtin_amdgcn_s_barrier();   // reads done; next half may overwrite Pf
        }
        return;
    }

    // ================= PV BLOCK (unchanged from R12) =================
    const int nl = id / 5;                       // 0..2047
    const int bh = nl >> 6, rr = nl & 63;
    const int qt = rr >> 1, jh2 = rr & 1;
    const int b = bh >> 4, h = bh & 15;
    const int q0 = qt * 64;
    const int jbase = jh2 * 1024;
    const int jh = w & 1, qh = w >> 1;
    const float slope = exp2f(-(float)(h + 1));
    const size_t kvbase = (size_t)bh * SS * 64;
    const size_t vtbase = (size_t)bh * 64 * SS;
    const float C  = slope * L2E;
    const float C64 = C * 64.f;
    bf16* opart = jh2 == 0 ? opart0 : opart1;
    bf16 (*ring)[64*64] = lds;

    bf16x8 aq[2][2];
    float lgl[2];
    #pragma unroll
    for (int cbq = 0; cbq < 2; ++cbq) {
        const int qi = q0 + qh*32 + cbq*16 + li;
        const bf16* qptr = Q + kvbase + (size_t)qi * 64;
        aq[cbq][0] = *(const bf16x8*)(qptr + lg*8);
        aq[cbq][1] = *(const bf16x8*)(qptr + 32 + lg*8);
        lgl[cbq] = Lbuf[(size_t)bh*SS + qi];
    }

    #define STAGE_K(J0, DST) do {                                              \
        _Pragma("unroll")                                                      \
        for (int i_ = 0; i_ < 2; ++i_) {                                       \
            int f_ = i_*256 + t; int row_ = f_ >> 3, c_ = f_ & 7;              \
            GLD16(Kk + kvbase + (size_t)((J0) + row_)*64 + (c_ ^ (row_ & 7))*8,\
                  (DST) + f_*8);                                               \
        } } while (0)
    #define STAGE_V(J0, DST) do {                                              \
        _Pragma("unroll")                                                      \
        for (int i_ = 0; i_ < 2; ++i_) {                                       \
            int f_ = i_*256 + t; int row_ = f_ >> 3, c_ = f_ & 7;              \
            GLD16(Vt + vtbase + (size_t)row_*SS + (J0) + (c_ ^ (row_ & 7))*8,  \
                  (DST) + f_*8);                                               \
        } } while (0)

    float ecr[2][2][4];
    #pragma unroll
    for (int jt = 0; jt < 2; ++jt)
        #pragma unroll
        for (int cbq = 0; cbq < 2; ++cbq)
            #pragma unroll
            for (int r = 0; r < 4; ++r)
                ecr[jt][cbq][r] = C * (float)(jbase + jh*32 + jt*16 + lg*4 + r - (SS-1)) - lgl[cbq];

    f32x4 acc[2][4] = {};

    STAGE_K(jbase, &ring[0][0]);
    STAGE_V(jbase, &ring[2][0]);
    __syncthreads();
    for (int kt = 0; kt < 16; ++kt) {
        const int cur = kt & 1;
        const int j0 = jbase + kt * 64;
        if (kt + 1 < 16) {
            STAGE_K(j0 + 64, &ring[cur ^ 1][0]);
            STAGE_V(j0 + 64, &ring[2 + (cur ^ 1)][0]);
        }
        const char* Ksb = (const char*)&ring[cur][0];
        const char* Vsb = (const char*)&ring[2 + cur][0];
        bf16x8 ak[2][2];
        #pragma unroll
        for (int jt = 0; jt < 2; ++jt) {
            int row = jh*32 + jt*16 + li;
            ak[jt][0] = *(const bf16x8*)(Ksb + row*128 + ((     lg*16) ^ swz));
            ak[jt][1] = *(const bf16x8*)(Ksb + row*128 + ((64 + lg*16) ^ swz));
        }
        f32x4 sc[2][2] = {};
        __builtin_amdgcn_s_setprio(1);
        #pragma unroll
        for (int jt = 0; jt < 2; ++jt)
            #pragma unroll
            for (int cbq = 0; cbq < 2; ++cbq) {
                sc[jt][cbq] = __builtin_amdgcn_mfma_f32_16x16x32_bf16(ak[jt][0], aq[cbq][0], sc[jt][cbq], 0,0,0);
                sc[jt][cbq] = __builtin_amdgcn_mfma_f32_16x16x32_bf16(ak[jt][1], aq[cbq][1], sc[jt][cbq], 0,0,0);
            }
        __builtin_amdgcn_s_setprio(0);
        bf16x8 pa[2];
        #pragma unroll
        for (int cbq = 0; cbq < 2; ++cbq) {
            bf16x8 p;
            #pragma unroll
            for (int jt = 0; jt < 2; ++jt) {
                p[jt*4+0] = (bf16)__builtin_amdgcn_exp2f(fmaf(sc[jt][cbq][0], K1, ecr[jt][cbq][0]));
                p[jt*4+1] = (bf16)__builtin_amdgcn_exp2f(fmaf(sc[jt][cbq][1], K1, ecr[jt][cbq][1]));
                p[jt*4+2] = (bf16)__builtin_amdgcn_exp2f(fmaf(sc[jt][cbq][2], K1, ecr[jt][cbq][2]));
                p[jt*4+3] = (bf16)__builtin_amdgcn_exp2f(fmaf(sc[jt][cbq][3], K1, ecr[jt][cbq][3]));
            }
            pa[cbq] = p;
        }
        #pragma unroll
        for (int jt = 0; jt < 2; ++jt)
            #pragma unroll
            for (int cbq = 0; cbq < 2; ++cbq) {
                ecr[jt][cbq][0] += C64; ecr[jt][cbq][1] += C64;
                ecr[jt][cbq][2] += C64; ecr[jt][cbq][3] += C64;
            }
        bf16x8 vb[4];
        #pragma unroll
        for (int d0 = 0; d0 < 4; ++d0) {
            int row = d0*16 + li;
            uint2 u0 = *(const uint2*)(Vsb + row*128 + ((jh*64      + lg*8) ^ swz));
            uint2 u1 = *(const uint2*)(Vsb + row*128 + ((jh*64 + 32 + lg*8) ^ swz));
            uint4 uu = {u0.x, u0.y, u1.x, u1.y};
            vb[d0] = __builtin_bit_cast(bf16x8, uu);
        }
        __builtin_amdgcn_s_setprio(1);
        #pragma unroll
        for (int cbq = 0; cbq < 2; ++cbq)
            #pragma unroll
            for (int d0 = 0; d0 < 4; ++d0)
                acc[cbq][d0] = __builtin_amdgcn_mfma_f32_16x16x32_bf16(pa[cbq], vb[d0], acc[cbq][d0], 0,0,0);
        __builtin_amdgcn_s_setprio(0);
        __syncthreads();
    }

    bf16* Obuf = &ring[0][0];
    #pragma unroll
    for (int cbq = 0; cbq < 2; ++cbq)
        #pragma unroll
        for (int d0 = 0; d0 < 4; ++d0)
            #pragma unroll
            for (int r = 0; r < 4; ++r)
                Obuf[jh*4096 + (qh*32 + cbq*16 + lg*4 + r)*64 + d0*16 + li] =
                    (bf16)acc[cbq][d0][r];
    __syncthreads();
    {
        int q = t >> 2, dc = (t & 3) << 4;
        const bf16* o0 = Obuf +        q*64 + dc;
        const bf16* o1 = Obuf + 4096 + q*64 + dc;
        bf16x8 a0 = *(const bf16x8*)(o0),     a1 = *(const bf16x8*)(o0 + 8);
        bf16x8 b0 = *(const bf16x8*)(o1),     b1 = *(const bf16x8*)(o1 + 8);
        bf16 ov[16];
        #pragma unroll
        for (int e = 0; e < 8; ++e) {
            ov[e]     = (bf16)((float)a0[e] + (float)b0[e]);
            ov[8 + e] = (bf16)((float)a1[e] + (float)b1[e]);
        }
        bf16* dst = opart + ((size_t)(b*SS + q0 + q))*EE + h*64 + dc;
        *(uint4*)(dst)     = *(uint4*)(ov);
        *(uint4*)(dst + 8) = *(uint4*)(ov + 8);
    }
    #undef STAGE_K
    #undef STAGE_V
}

// ---------------- ORED: Ab = Opart0 + Opart1 (bf16, x8 vectorized) ----------
__global__ __launch_bounds__(256) void ored_kernel(const bf16* __restrict__ O0,
                                                   const bf16* __restrict__ O1,
                                                   bf16* __restrict__ Ab) {
    int i = (blockIdx.x * 256 + threadIdx.x) * 8;   // 2048 blocks -> 4.19M elems
    bf16x8 a = *(const bf16x8*)(O0 + i);
    bf16x8 b = *(const bf16x8*)(O1 + i);
    bf16 o[8];
    #pragma unroll
    for (int e = 0; e < 8; ++e) o[e] = (bf16)((float)a[e] + (float)b[e]);
    *(uint4*)(Ab + i) = *(uint4*)o;
}

// ---------------- launcher ----------------
extern "C" void kernel_launch(void* const* d_in, const int* in_sizes, int n_in,
                              void* d_out, int out_size, void* d_ws, size_t ws_size,
                              hipStream_t stream) {
    const float* x   = (const float*)d_in[0];
    const float* Wq  = (const float*)d_in[1];
    const float* bq  = (const float*)d_in[2];
    const float* Wk  = (const float*)d_in[3];
    const float* bk  = (const float*)d_in[4];
    const float* Wv  = (const float*)d_in[5];
    const float* bv  = (const float*)d_in[6];
    const float* Wfc = (const float*)d_in[7];
    const float* bfc = (const float*)d_in[8];

    char* ws = (char*)d_ws;
    const size_t MB = 1024u*1024u;
    bf16* xb   = (bf16*)(ws + 0);        // 8 MB; dead after QKV -> Opart0
    bf16* wqb  = (bf16*)(ws + 8*MB);     // 2 MB; dead after QKV -> Lpart/Lbuf
    bf16* wkb  = (bf16*)(ws + 10*MB);
    bf16* wvb  = (bf16*)(ws + 12*MB);
    bf16* wfb  = (bf16*)(ws + 14*MB);    // alive until fc
    bf16* Qb   = (bf16*)(ws + 16*MB);    // 8 MB  [B*H][S][64]
    bf16* Kb   = (bf16*)(ws + 24*MB);    // 8 MB
    bf16* Vb   = (bf16*)(ws + 32*MB);    // 8 MB; dead after transpose -> Opart1
    bf16* Vtb  = (bf16*)(ws + 40*MB);    // 8 MB  [B*H][64][S]
    bf16* Ab   = (bf16*)(ws + 48*MB);    // 8 MB  [B][S][E]
    bf16* Opart0 = (bf16*)(ws + 0);      // reuse xb
    bf16* Opart1 = (bf16*)(ws + 32*MB);  // reuse Vb
    float* Lpart = (float*)(ws + 8*MB);  // 512 KB (reuse wqb)
    float* Lb    = (float*)(ws + 9*MB);  // 256 KB (reuse wqb tail)

    float* outp = (float*)d_out;
    float* wout = outp + (size_t)BB*SS*EE;

    cvt_f32_bf16<<<dim3(4194304/8/256), 256, 0, stream>>>(x, xb, 4194304);
    cvt4<<<dim3(512, 4), 256, 0, stream>>>(Wq, Wk, Wv, Wfc, wqb, wkb, wvb, wfb);

    gemm128<0><<<dim3(24, 32), 256, 0, stream>>>(xb, wqb, wkb, wvb, bq, bk, bv, Qb, Kb, Vb);

    transpose_v<<<dim3(SS/64, BB*HH), 256, 0, stream>>>(Vb, Vtb);

    lsum_kernel<<<dim3(64, 32), 256, 0, stream>>>(Qb, Kb, Lpart);
    lfix_kernel<<<dim3(64), 1024, 0, stream>>>(Lpart, Lb);

    fat_kernel<<<dim3(10240), 256, 0, stream>>>(Qb, Kb, Vtb, Lb, wout, Opart0, Opart1);

    ored_kernel<<<dim3(2048), 256, 0, stream>>>(Opart0, Opart1, Ab);

    gemm128<1><<<dim3(8, 32), 256, 0, stream>>>(Ab, wfb, wfb, wfb, bfc, bfc, bfc, d_out, d_out, d_out);
}